// Round 1
// baseline (530.425 us; speedup 1.0000x reference)
//
#include <hip/hip_runtime.h>
#include <stdint.h>

// ---- JAX PRNG variant: 1 = threefry_partitionable (modern JAX default),
//                        0 = original split-in-half counter scheme
#define JAX_PARTITIONABLE 1

#define N_IMG 8
#define K_ANC 9
#define HW_G 14400
#define W_G 120
#define A_TOT 129600
#define M_GT 64
#define NBIN 4096
#define CAP 2048

static constexpr size_t OFF_KEYS  = 0;                                  // u32[8][4] kp0,kp1,kn0,kn1
static constexpr size_t OFF_MATCH = 256;                                // i32[8][A]
static constexpr size_t OFF_POSB  = OFF_MATCH + 4ull * N_IMG * A_TOT;   // u32[8][A]
static constexpr size_t OFF_NEGB  = OFF_POSB  + 4ull * N_IMG * A_TOT;   // u32[8][A]
static constexpr size_t OFF_PHIST = OFF_NEGB  + 4ull * N_IMG * A_TOT;   // u32[8][4096]
static constexpr size_t OFF_NHIST = OFF_PHIST + 4ull * N_IMG * NBIN;    // u32[8][4096]
static constexpr size_t OFF_IMG   = OFF_NHIST + 4ull * N_IMG * NBIN;    // f32[8][5]

__device__ __forceinline__ uint32_t rotl32(uint32_t v, int r) {
  return (v << r) | (v >> (32 - r));
}

// threefry2x32, 20 rounds, exact JAX/Random123 schedule
__device__ void tf2x32(uint32_t k0, uint32_t k1, uint32_t x0, uint32_t x1,
                       uint32_t& o0, uint32_t& o1) {
  uint32_t ks2 = 0x1BD11BDAu ^ k0 ^ k1;
  x0 += k0; x1 += k1;
#define TF_R(r) { x0 += x1; x1 = rotl32(x1, r); x1 ^= x0; }
  TF_R(13) TF_R(15) TF_R(26) TF_R(6)
  x0 += k1; x1 += ks2 + 1u;
  TF_R(17) TF_R(29) TF_R(16) TF_R(24)
  x0 += ks2; x1 += k0 + 2u;
  TF_R(13) TF_R(15) TF_R(26) TF_R(6)
  x0 += k0; x1 += k1 + 3u;
  TF_R(17) TF_R(29) TF_R(16) TF_R(24)
  x0 += k1; x1 += ks2 + 4u;
  TF_R(13) TF_R(15) TF_R(26) TF_R(6)
  x0 += ks2; x1 += k0 + 5u;
#undef TF_R
  o0 = x0; o1 = x1;
}

// anchor box + clipped region for (image n, flat anchor a)
__device__ __forceinline__ void anchor_region(
    int n, int a, const float* __restrict__ del,
    float& ax1, float& ay1, float& ax2, float& ay2,
    float& rx1, float& ry1, float& rx2, float& ry2, int& k_out, int& hw_out) {
  int k = a % K_ANC; int hw = a / K_ANC;
  int w = hw % W_G; int h = hw / W_G;
  const float scales[3] = {8.f, 16.f, 32.f};
  const float ratios[3] = {0.5f, 1.f, 2.f};
  float sc = scales[k % 3];      // k = ratio_idx*3 + scale_idx
  float rt = ratios[k / 3];
  float wsz = (16.f * sc) * sqrtf(1.f / rt);
  float hsz = (16.f * sc) * sqrtf(rt);
  float cx = ((float)w + 0.5f) * 16.f;
  float cy = ((float)h + 0.5f) * 16.f;
  ax1 = cx - wsz * 0.5f; ay1 = cy - hsz * 0.5f;
  ax2 = cx + wsz * 0.5f; ay2 = cy + hsz * 0.5f;
  int base = (n * 36 + k * 4) * HW_G + hw;
  float d0 = del[base];
  float d1 = del[base + HW_G];
  float d2 = del[base + 2 * HW_G];
  float d3 = del[base + 3 * HW_G];
  rx1 = fminf(fmaxf(ax1 + d0, 0.f), 1920.f);
  ry1 = fminf(fmaxf(ay1 + d1, 0.f), 1920.f);
  rx2 = fminf(fmaxf(ax2 + d2, 0.f), 1920.f);
  ry2 = fminf(fmaxf(ay2 + d3, 0.f), 1920.f);
  k_out = k; hw_out = hw;
}

__device__ void accum_pos(int n, int a, const float* __restrict__ cls,
                          const float* __restrict__ del, const float* __restrict__ gt,
                          const int* __restrict__ match,
                          float* sSp, float* sPred, float* sL1) {
  float ax1, ay1, ax2, ay2, rx1, ry1, rx2, ry2; int k, hw;
  anchor_region(n, a, del, ax1, ay1, ax2, ay2, rx1, ry1, rx2, ry2, k, hw);
  float L = cls[(n * K_ANC + k) * HW_G + hw];
  // softplus(-L)
  atomicAdd(sSp, fmaxf(-L, 0.f) + log1pf(expf(-fabsf(L))));
  atomicAdd(sPred, L);
  int m = match[n * A_TOT + a];
  const float* g = gt + (n * M_GT + m) * 4;
  float aw = ax2 - ax1, ah = ay2 - ay1;
  float acx = ax1 + 0.5f * aw, acy = ay1 + 0.5f * ah;
  float bw = fmaxf(rx2 - rx1, 1e-6f), bh = fmaxf(ry2 - ry1, 1e-6f);
  float bcx = rx1 + 0.5f * bw, bcy = ry1 + 0.5f * bh;
  float gw = fmaxf(g[2] - g[0], 1e-6f), gh = fmaxf(g[3] - g[1], 1e-6f);
  float gcx = g[0] + 0.5f * gw, gcy = g[1] + 0.5f * gh;
  float dd0 = (bcx - acx) / aw - (gcx - acx) / aw;
  float dd1 = (bcy - acy) / ah - (gcy - acy) / ah;
  float dd2 = logf(bw / aw) - logf(gw / aw);
  float dd3 = logf(bh / ah) - logf(gh / ah);
  float dd[4] = {dd0, dd1, dd2, dd3};
  float l1 = 0.f;
  for (int i = 0; i < 4; ++i) {
    float ad = fabsf(dd[i]);
    l1 += (ad < 0.1f) ? (0.5f * dd[i] * dd[i] / 0.1f) : (ad - 0.05f);
  }
  atomicAdd(sL1, l1);
}

__device__ void accum_neg(int n, int a, const float* __restrict__ cls,
                          float* sSp, float* sPred) {
  int k = a % K_ANC; int hw = a / K_ANC;
  float L = cls[(n * K_ANC + k) * HW_G + hw];
  // softplus(L)
  atomicAdd(sSp, fmaxf(L, 0.f) + log1pf(expf(-fabsf(L))));
  atomicAdd(sPred, L);
}

// ---------------------------------------------------------------------------
__global__ void k_init(uint8_t* ws) {
  uint32_t* hist = (uint32_t*)(ws + OFF_PHIST);  // phist+nhist contiguous
  int gid = blockIdx.x * blockDim.x + threadIdx.x;
  if (gid < 2 * N_IMG * NBIN) hist[gid] = 0u;
  if (gid == 0) {
    uint32_t* keys = (uint32_t*)(ws + OFF_KEYS);
#if JAX_PARTITIONABLE
    for (int n = 0; n < N_IMG; ++n) {
      uint32_t i0, i1;
      tf2x32(0u, 42u, 0u, (uint32_t)n, i0, i1);       // fold-like split of key(42)
      uint32_t p0, p1, q0, q1;
      tf2x32(i0, i1, 0u, 0u, p0, p1);                 // kp
      tf2x32(i0, i1, 0u, 1u, q0, q1);                 // kn
      keys[n * 4 + 0] = p0; keys[n * 4 + 1] = p1;
      keys[n * 4 + 2] = q0; keys[n * 4 + 3] = q1;
    }
#else
    uint32_t y0[8], y1[8];
    for (int j = 0; j < 8; ++j)
      tf2x32(0u, 42u, (uint32_t)j, (uint32_t)(8 + j), y0[j], y1[j]);
    uint32_t cat[16];
    for (int j = 0; j < 8; ++j) { cat[j] = y0[j]; cat[8 + j] = y1[j]; }
    for (int n = 0; n < N_IMG; ++n) {
      uint32_t i0 = cat[2 * n], i1 = cat[2 * n + 1];
      uint32_t a0, a1, b0, b1;
      tf2x32(i0, i1, 0u, 2u, a0, a1);  // pairs (0,2) and (1,3) of iota(4)
      tf2x32(i0, i1, 1u, 3u, b0, b1);
      keys[n * 4 + 0] = a0; keys[n * 4 + 1] = b0;   // kp = (y0_0, y0_1)
      keys[n * 4 + 2] = a1; keys[n * 4 + 3] = b1;   // kn = (y1_0, y1_1)
    }
#endif
  }
}

__global__ __launch_bounds__(256) void k_match(
    const float* __restrict__ cls, const float* __restrict__ del,
    const float* __restrict__ gt, uint8_t* ws) {
  int n = blockIdx.y;
  int a = blockIdx.x * blockDim.x + threadIdx.x;
  __shared__ float gx1[M_GT], gy1[M_GT], gx2[M_GT], gy2[M_GT], gar[M_GT];
  if (threadIdx.x < M_GT) {
    int j = threadIdx.x;
    float x1 = gt[(n * M_GT + j) * 4 + 0];
    float y1 = gt[(n * M_GT + j) * 4 + 1];
    float x2 = gt[(n * M_GT + j) * 4 + 2];
    float y2 = gt[(n * M_GT + j) * 4 + 3];
    gx1[j] = x1; gy1[j] = y1; gx2[j] = x2; gy2[j] = y2;
    gar[j] = fmaxf(x2 - x1, 0.f) * fmaxf(y2 - y1, 0.f);
  }
  __syncthreads();
  if (a >= A_TOT) return;

  float ax1, ay1, ax2, ay2, rx1, ry1, rx2, ry2; int k, hw;
  anchor_region(n, a, del, ax1, ay1, ax2, ay2, rx1, ry1, rx2, ry2, k, hw);
  float ab = fmaxf(rx2 - rx1, 0.f) * fmaxf(ry2 - ry1, 0.f);
  float best = -1.f; int arg = 0;
  for (int j = 0; j < M_GT; ++j) {
    float ix1 = fmaxf(rx1, gx1[j]);
    float iy1 = fmaxf(ry1, gy1[j]);
    float ix2 = fminf(rx2, gx2[j]);
    float iy2 = fminf(ry2, gy2[j]);
    float inter = fmaxf(ix2 - ix1, 0.f) * fmaxf(iy2 - iy1, 0.f);
    float iou = inter / (ab + gar[j] - inter + 1e-6f);
    if (iou > best) { best = iou; arg = j; }   // first-max (argmax semantics)
  }
  int m = (best >= 0.4f) ? arg : ((best < 0.1f) ? -1 : -2);
  ((int*)(ws + OFF_MATCH))[n * A_TOT + a] = m;

  const uint32_t* keys = (const uint32_t*)(ws + OFF_KEYS) + n * 4;
  uint32_t kp0 = keys[0], kp1 = keys[1], kn0 = keys[2], kn1 = keys[3];
  uint32_t pbits, nbits;
#if JAX_PARTITIONABLE
  {
    uint32_t y0, y1;
    tf2x32(kp0, kp1, 0u, (uint32_t)a, y0, y1); pbits = (y0 ^ y1) >> 9;
    tf2x32(kn0, kn1, 0u, (uint32_t)a, y0, y1); nbits = (y0 ^ y1) >> 9;
  }
#else
  {
    const uint32_t half = A_TOT / 2;
    uint32_t j = (a < (int)half) ? (uint32_t)a : (uint32_t)a - half;
    uint32_t y0, y1;
    tf2x32(kp0, kp1, j, half + j, y0, y1);
    pbits = ((a < (int)half) ? y0 : y1) >> 9;
    tf2x32(kn0, kn1, j, half + j, y0, y1);
    nbits = ((a < (int)half) ? y0 : y1) >> 9;
  }
#endif
  uint32_t pentry = (m >= 0 && pbits != 0u) ? pbits : 0u;
  uint32_t nentry = (m == -1 && nbits != 0u) ? nbits : 0u;
  ((uint32_t*)(ws + OFF_POSB))[n * A_TOT + a] = pentry;
  ((uint32_t*)(ws + OFF_NEGB))[n * A_TOT + a] = nentry;
  if (pentry) atomicAdd(&((uint32_t*)(ws + OFF_PHIST))[n * NBIN + (pentry >> 11)], 1u);
  if (nentry) atomicAdd(&((uint32_t*)(ws + OFF_NHIST))[n * NBIN + (nentry >> 11)], 1u);
}

__global__ __launch_bounds__(256) void k_select(
    const float* __restrict__ cls, const float* __restrict__ del,
    const float* __restrict__ gt, uint8_t* ws) {
  int n = blockIdx.x;
  int tid = threadIdx.x;
  const int* match = (const int*)(ws + OFF_MATCH);
  const uint32_t* posb = (const uint32_t*)(ws + OFF_POSB);
  const uint32_t* negb = (const uint32_t*)(ws + OFF_NEGB);
  float* imgout = (float*)(ws + OFF_IMG);

  __shared__ uint32_t shist[NBIN];
  __shared__ uint32_t chunk[256];
  __shared__ unsigned long long buf[2][CAP];
  __shared__ unsigned long long red64[256];
  __shared__ int cnt[2];
  __shared__ int sB[2], sNeed[2], sK[2];
  __shared__ float sSp, sPred, sL1;
  if (tid == 0) { sSp = 0.f; sPred = 0.f; sL1 = 0.f; cnt[0] = 0; cnt[1] = 0; }

  // exact k-th threshold (bin) for pos (k=128) and neg (k=60)
  for (int which = 0; which < 2; ++which) {
    const uint32_t* hsrc =
        (const uint32_t*)(ws + (which == 0 ? OFF_PHIST : OFF_NHIST)) + n * NBIN;
    __syncthreads();
    for (int i = tid; i < NBIN; i += 256) shist[i] = hsrc[i];
    __syncthreads();
    uint32_t cs = 0;
    for (int i = 0; i < 16; ++i) cs += shist[tid * 16 + i];
    chunk[tid] = cs;
    __syncthreads();
    if (tid == 0) {
      int kk = (which == 0) ? 128 : 60;
      unsigned c = 0; int b = -1; int need = 0;
      for (int t = 255; t >= 0; --t) {
        unsigned cc = chunk[t];
        if (c + cc >= (unsigned)kk) {
          for (int i = t * 16 + 15;; --i) {
            unsigned hc = shist[i];
            if (c + hc >= (unsigned)kk) { b = i; need = kk - (int)c; break; }
            c += hc;
          }
          break;
        }
        c += cc;
      }
      sB[which] = b; sNeed[which] = need;
      sK[which] = (b < 0) ? (int)c : kk;
    }
    __syncthreads();
  }

  int bPos = sB[0], bNeg = sB[1];
  // scan: accumulate strictly-above-boundary candidates, stash boundary bin
  for (int a = tid; a < A_TOT; a += 256) {
    uint32_t pb = posb[n * A_TOT + a];
    if (pb) {
      int bin = (int)(pb >> 11);
      if (bPos < 0 || bin > bPos) {
        accum_pos(n, a, cls, del, gt, match, &sSp, &sPred, &sL1);
      } else if (bin == bPos) {
        int i = atomicAdd(&cnt[0], 1);
        if (i < CAP)
          buf[0][i] = ((unsigned long long)pb << 17) | (unsigned)(0x1FFFF - a);
      }
    }
    uint32_t nb = negb[n * A_TOT + a];
    if (nb) {
      int bin = (int)(nb >> 11);
      if (bNeg < 0 || bin > bNeg) {
        accum_neg(n, a, cls, &sSp, &sPred);
      } else if (bin == bNeg) {
        int i = atomicAdd(&cnt[1], 1);
        if (i < CAP)
          buf[1][i] = ((unsigned long long)nb << 17) | (unsigned)(0x1FFFF - a);
      }
    }
  }
  __syncthreads();

  // boundary bin: take top `need` by (bits desc, index asc) via argmax loop
  for (int which = 0; which < 2; ++which) {
    int need = sNeed[which];
    int m = min(cnt[which], CAP);
    for (int it = 0; it < need; ++it) {
      unsigned long long best = 0ull;
      for (int i = tid; i < m; i += 256)
        if (buf[which][i] > best) best = buf[which][i];
      red64[tid] = best;
      __syncthreads();
      for (int s = 128; s > 0; s >>= 1) {
        if (tid < s && red64[tid + s] > red64[tid]) red64[tid] = red64[tid + s];
        __syncthreads();
      }
      unsigned long long key = red64[0];
      __syncthreads();
      for (int i = tid; i < m; i += 256) {
        if (buf[which][i] == key && key != 0ull) {
          buf[which][i] = 0ull;
          int aa = 0x1FFFF - (int)(key & 0x1FFFFull);
          if (which == 0) accum_pos(n, aa, cls, del, gt, match, &sSp, &sPred, &sL1);
          else            accum_neg(n, aa, cls, &sSp, &sPred);
        }
      }
      __syncthreads();
    }
  }
  __syncthreads();

  if (tid == 0) {
    float npos = (float)sK[0], nneg = (float)sK[1];
    float denom = fmaxf(npos + nneg, 1.f);
    imgout[n * 5 + 0] = sSp / denom;
    imgout[n * 5 + 1] = sL1 / (fmaxf(npos, 1.f) * 8.0f);   // n_norm = N = 8
    imgout[n * 5 + 2] = npos;
    imgout[n * 5 + 3] = nneg;
    imgout[n * 5 + 4] = sPred / denom;
  }
}

__global__ void k_final(const uint8_t* ws, float* out) {
  if (blockIdx.x == 0 && threadIdx.x == 0) {
    const float* io = (const float*)(ws + OFF_IMG);
    float c = 0.f, b = 0.f, fg = 0.f, bg = 0.f;
    for (int n = 0; n < N_IMG; ++n) {
      c += io[n * 5 + 0];
      b += io[n * 5 + 1];
      fg += io[n * 5 + 2];
      bg += io[n * 5 + 3];
    }
    out[0] = c;                 // cls_loss sum
    out[1] = b;                 // bbox_loss sum
    out[2] = bg;                // nneg sum (bg)
    out[3] = fg;                // npos sum (fg)
    out[4] = io[7 * 5 + 4];     // pred_mean of last image
  }
}

extern "C" void kernel_launch(void* const* d_in, const int* in_sizes, int n_in,
                              void* d_out, int out_size, void* d_ws, size_t ws_size,
                              hipStream_t stream) {
  (void)in_sizes; (void)n_in; (void)out_size; (void)ws_size;
  const float* cls = (const float*)d_in[0];
  const float* del = (const float*)d_in[1];
  const float* gt  = (const float*)d_in[2];
  float* out = (float*)d_out;
  uint8_t* ws = (uint8_t*)d_ws;

  hipLaunchKernelGGL(k_init, dim3(256), dim3(256), 0, stream, ws);
  hipLaunchKernelGGL(k_match, dim3((A_TOT + 255) / 256, N_IMG), dim3(256), 0, stream,
                     cls, del, gt, ws);
  hipLaunchKernelGGL(k_select, dim3(N_IMG), dim3(256), 0, stream, cls, del, gt, ws);
  hipLaunchKernelGGL(k_final, dim3(1), dim3(64), 0, stream, ws, out);
}

// Round 2
// 174.773 us; speedup vs baseline: 3.0349x; 3.0349x over previous
//
#include <hip/hip_runtime.h>
#include <stdint.h>

#define JAX_PARTITIONABLE 1

#define N_IMG 8
#define K_ANC 9
#define HW_G 14400
#define W_G 120
#define A_TOT 129600
#define M_GT 64
#define NBIN 4096
#define CAP 2048

static constexpr size_t OFF_KEYS  = 0;                                  // u32[8][4]
static constexpr size_t OFF_MATCH = 256;                                // i32[8][A]
static constexpr size_t OFF_POSB  = OFF_MATCH + 4ull * N_IMG * A_TOT;   // u32[8][A]
static constexpr size_t OFF_NEGB  = OFF_POSB  + 4ull * N_IMG * A_TOT;   // u32[8][A]
static constexpr size_t OFF_PHIST = OFF_NEGB  + 4ull * N_IMG * A_TOT;   // u32[8][4096]
static constexpr size_t OFF_NHIST = OFF_PHIST + 4ull * N_IMG * NBIN;    // u32[8][4096]
static constexpr size_t OFF_THR   = OFF_NHIST + 4ull * N_IMG * NBIN;    // i32[8][2][3]
static constexpr size_t OFF_CNT   = OFF_THR + 256;                      // i32[8][2]
static constexpr size_t OFF_ACC   = OFF_CNT + 64;                       // f32[8][4] sp,pred,l1
static constexpr size_t OFF_BND   = OFF_ACC + 128;                      // u64[8][2][CAP]
// zero-init span: OFF_PHIST .. OFF_BND (hists + thr + cnt + acc)
static constexpr int ZERO_U32 = (int)((OFF_BND - OFF_PHIST) / 4);

__device__ __forceinline__ uint32_t rotl32(uint32_t v, int r) {
  return (v << r) | (v >> (32 - r));
}

// threefry2x32, 20 rounds, exact JAX/Random123 schedule
__device__ void tf2x32(uint32_t k0, uint32_t k1, uint32_t x0, uint32_t x1,
                       uint32_t& o0, uint32_t& o1) {
  uint32_t ks2 = 0x1BD11BDAu ^ k0 ^ k1;
  x0 += k0; x1 += k1;
#define TF_R(r) { x0 += x1; x1 = rotl32(x1, r); x1 ^= x0; }
  TF_R(13) TF_R(15) TF_R(26) TF_R(6)
  x0 += k1; x1 += ks2 + 1u;
  TF_R(17) TF_R(29) TF_R(16) TF_R(24)
  x0 += ks2; x1 += k0 + 2u;
  TF_R(13) TF_R(15) TF_R(26) TF_R(6)
  x0 += k0; x1 += k1 + 3u;
  TF_R(17) TF_R(29) TF_R(16) TF_R(24)
  x0 += k1; x1 += ks2 + 4u;
  TF_R(13) TF_R(15) TF_R(26) TF_R(6)
  x0 += ks2; x1 += k0 + 5u;
#undef TF_R
  o0 = x0; o1 = x1;
}

__device__ __forceinline__ void anchor_region(
    int n, int a, const float* __restrict__ del,
    float& ax1, float& ay1, float& ax2, float& ay2,
    float& rx1, float& ry1, float& rx2, float& ry2, int& k_out, int& hw_out) {
  int k = a % K_ANC; int hw = a / K_ANC;
  int w = hw % W_G; int h = hw / W_G;
  const float scales[3] = {8.f, 16.f, 32.f};
  const float ratios[3] = {0.5f, 1.f, 2.f};
  float sc = scales[k % 3];
  float rt = ratios[k / 3];
  float wsz = (16.f * sc) * sqrtf(1.f / rt);
  float hsz = (16.f * sc) * sqrtf(rt);
  float cx = ((float)w + 0.5f) * 16.f;
  float cy = ((float)h + 0.5f) * 16.f;
  ax1 = cx - wsz * 0.5f; ay1 = cy - hsz * 0.5f;
  ax2 = cx + wsz * 0.5f; ay2 = cy + hsz * 0.5f;
  int base = (n * 36 + k * 4) * HW_G + hw;
  float d0 = del[base];
  float d1 = del[base + HW_G];
  float d2 = del[base + 2 * HW_G];
  float d3 = del[base + 3 * HW_G];
  rx1 = fminf(fmaxf(ax1 + d0, 0.f), 1920.f);
  ry1 = fminf(fmaxf(ay1 + d1, 0.f), 1920.f);
  rx2 = fminf(fmaxf(ax2 + d2, 0.f), 1920.f);
  ry2 = fminf(fmaxf(ay2 + d3, 0.f), 1920.f);
  k_out = k; hw_out = hw;
}

// accumulate into global per-image acc = {sp, pred, l1, pad}
__device__ void accum_pos(int n, int a, const float* __restrict__ cls,
                          const float* __restrict__ del, const float* __restrict__ gt,
                          const int* __restrict__ match, float* acc) {
  float ax1, ay1, ax2, ay2, rx1, ry1, rx2, ry2; int k, hw;
  anchor_region(n, a, del, ax1, ay1, ax2, ay2, rx1, ry1, rx2, ry2, k, hw);
  float L = cls[(n * K_ANC + k) * HW_G + hw];
  atomicAdd(&acc[0], fmaxf(-L, 0.f) + log1pf(expf(-fabsf(L))));  // softplus(-L)
  atomicAdd(&acc[1], L);
  int m = match[n * A_TOT + a];
  const float* g = gt + (n * M_GT + m) * 4;
  float aw = ax2 - ax1, ah = ay2 - ay1;
  float acx = ax1 + 0.5f * aw, acy = ay1 + 0.5f * ah;
  float bw = fmaxf(rx2 - rx1, 1e-6f), bh = fmaxf(ry2 - ry1, 1e-6f);
  float bcx = rx1 + 0.5f * bw, bcy = ry1 + 0.5f * bh;
  float gw = fmaxf(g[2] - g[0], 1e-6f), gh = fmaxf(g[3] - g[1], 1e-6f);
  float gcx = g[0] + 0.5f * gw, gcy = g[1] + 0.5f * gh;
  float dd[4];
  dd[0] = (bcx - acx) / aw - (gcx - acx) / aw;
  dd[1] = (bcy - acy) / ah - (gcy - acy) / ah;
  dd[2] = logf(bw / aw) - logf(gw / aw);
  dd[3] = logf(bh / ah) - logf(gh / ah);
  float l1 = 0.f;
  for (int i = 0; i < 4; ++i) {
    float ad = fabsf(dd[i]);
    l1 += (ad < 0.1f) ? (0.5f * dd[i] * dd[i] / 0.1f) : (ad - 0.05f);
  }
  atomicAdd(&acc[2], l1);
}

__device__ void accum_neg(int n, int a, const float* __restrict__ cls, float* acc) {
  int k = a % K_ANC; int hw = a / K_ANC;
  float L = cls[(n * K_ANC + k) * HW_G + hw];
  atomicAdd(&acc[0], fmaxf(L, 0.f) + log1pf(expf(-fabsf(L))));   // softplus(L)
  atomicAdd(&acc[1], L);
}

// ---------------------------------------------------------------------------
__global__ void k_init(uint8_t* ws) {
  uint32_t* z = (uint32_t*)(ws + OFF_PHIST);
  int gid = blockIdx.x * blockDim.x + threadIdx.x;
  if (gid < ZERO_U32) z[gid] = 0u;
  if (gid == 0) {
    uint32_t* keys = (uint32_t*)(ws + OFF_KEYS);
#if JAX_PARTITIONABLE
    for (int n = 0; n < N_IMG; ++n) {
      uint32_t i0, i1;
      tf2x32(0u, 42u, 0u, (uint32_t)n, i0, i1);
      uint32_t p0, p1, q0, q1;
      tf2x32(i0, i1, 0u, 0u, p0, p1);
      tf2x32(i0, i1, 0u, 1u, q0, q1);
      keys[n * 4 + 0] = p0; keys[n * 4 + 1] = p1;
      keys[n * 4 + 2] = q0; keys[n * 4 + 3] = q1;
    }
#else
    uint32_t y0[8], y1[8];
    for (int j = 0; j < 8; ++j)
      tf2x32(0u, 42u, (uint32_t)j, (uint32_t)(8 + j), y0[j], y1[j]);
    uint32_t cat[16];
    for (int j = 0; j < 8; ++j) { cat[j] = y0[j]; cat[8 + j] = y1[j]; }
    for (int n = 0; n < N_IMG; ++n) {
      uint32_t i0 = cat[2 * n], i1 = cat[2 * n + 1];
      uint32_t a0, a1, b0, b1;
      tf2x32(i0, i1, 0u, 2u, a0, a1);
      tf2x32(i0, i1, 1u, 3u, b0, b1);
      keys[n * 4 + 0] = a0; keys[n * 4 + 1] = b0;
      keys[n * 4 + 2] = a1; keys[n * 4 + 3] = b1;
    }
#endif
  }
}

__global__ __launch_bounds__(256) void k_match(
    const float* __restrict__ cls, const float* __restrict__ del,
    const float* __restrict__ gt, uint8_t* ws) {
  int n = blockIdx.y;
  int a = blockIdx.x * blockDim.x + threadIdx.x;
  __shared__ float gx1[M_GT], gy1[M_GT], gx2[M_GT], gy2[M_GT], gar[M_GT];
  if (threadIdx.x < M_GT) {
    int j = threadIdx.x;
    float x1 = gt[(n * M_GT + j) * 4 + 0];
    float y1 = gt[(n * M_GT + j) * 4 + 1];
    float x2 = gt[(n * M_GT + j) * 4 + 2];
    float y2 = gt[(n * M_GT + j) * 4 + 3];
    gx1[j] = x1; gy1[j] = y1; gx2[j] = x2; gy2[j] = y2;
    gar[j] = fmaxf(x2 - x1, 0.f) * fmaxf(y2 - y1, 0.f);
  }
  __syncthreads();
  if (a >= A_TOT) return;

  float ax1, ay1, ax2, ay2, rx1, ry1, rx2, ry2; int k, hw;
  anchor_region(n, a, del, ax1, ay1, ax2, ay2, rx1, ry1, rx2, ry2, k, hw);
  float ab = fmaxf(rx2 - rx1, 0.f) * fmaxf(ry2 - ry1, 0.f);
  float best = -1.f; int arg = 0;
  for (int j = 0; j < M_GT; ++j) {
    float ix1 = fmaxf(rx1, gx1[j]);
    float iy1 = fmaxf(ry1, gy1[j]);
    float ix2 = fminf(rx2, gx2[j]);
    float iy2 = fminf(ry2, gy2[j]);
    float inter = fmaxf(ix2 - ix1, 0.f) * fmaxf(iy2 - iy1, 0.f);
    float iou = inter / (ab + gar[j] - inter + 1e-6f);
    if (iou > best) { best = iou; arg = j; }
  }
  int m = (best >= 0.4f) ? arg : ((best < 0.1f) ? -1 : -2);
  ((int*)(ws + OFF_MATCH))[n * A_TOT + a] = m;

  const uint32_t* keys = (const uint32_t*)(ws + OFF_KEYS) + n * 4;
  uint32_t kp0 = keys[0], kp1 = keys[1], kn0 = keys[2], kn1 = keys[3];
  uint32_t pbits, nbits;
#if JAX_PARTITIONABLE
  {
    uint32_t y0, y1;
    tf2x32(kp0, kp1, 0u, (uint32_t)a, y0, y1); pbits = (y0 ^ y1) >> 9;
    tf2x32(kn0, kn1, 0u, (uint32_t)a, y0, y1); nbits = (y0 ^ y1) >> 9;
  }
#else
  {
    const uint32_t half = A_TOT / 2;
    uint32_t j = (a < (int)half) ? (uint32_t)a : (uint32_t)a - half;
    uint32_t y0, y1;
    tf2x32(kp0, kp1, j, half + j, y0, y1);
    pbits = ((a < (int)half) ? y0 : y1) >> 9;
    tf2x32(kn0, kn1, j, half + j, y0, y1);
    nbits = ((a < (int)half) ? y0 : y1) >> 9;
  }
#endif
  uint32_t pentry = (m >= 0 && pbits != 0u) ? pbits : 0u;
  uint32_t nentry = (m == -1 && nbits != 0u) ? nbits : 0u;
  ((uint32_t*)(ws + OFF_POSB))[n * A_TOT + a] = pentry;
  ((uint32_t*)(ws + OFF_NEGB))[n * A_TOT + a] = nentry;
  if (pentry) atomicAdd(&((uint32_t*)(ws + OFF_PHIST))[n * NBIN + (pentry >> 11)], 1u);
  if (nentry) atomicAdd(&((uint32_t*)(ws + OFF_NHIST))[n * NBIN + (nentry >> 11)], 1u);
}

// one block per (which, image): exact k-th threshold bin from 4096-bin histogram
__global__ __launch_bounds__(256) void k_thresh(uint8_t* ws) {
  int which = blockIdx.x, n = blockIdx.y, tid = threadIdx.x;
  const uint32_t* hsrc =
      (const uint32_t*)(ws + (which == 0 ? OFF_PHIST : OFF_NHIST)) + n * NBIN;
  __shared__ uint32_t shist[NBIN];
  __shared__ uint32_t chunk[256];
  for (int i = tid; i < NBIN; i += 256) shist[i] = hsrc[i];
  __syncthreads();
  uint32_t cs = 0;
  for (int i = 0; i < 16; ++i) cs += shist[tid * 16 + i];
  chunk[tid] = cs;
  __syncthreads();
  if (tid == 0) {
    int kk = (which == 0) ? 128 : 60;
    unsigned c = 0; int b = -1; int need = 0;
    for (int t = 255; t >= 0; --t) {
      unsigned cc = chunk[t];
      if (c + cc >= (unsigned)kk) {
        for (int i = t * 16 + 15;; --i) {
          unsigned hc = shist[i];
          if (c + hc >= (unsigned)kk) { b = i; need = kk - (int)c; break; }
          c += hc;
        }
        break;
      }
      c += cc;
    }
    int* thr = (int*)(ws + OFF_THR) + (n * 2 + which) * 3;
    thr[0] = b; thr[1] = need; thr[2] = (b < 0) ? (int)c : kk;
  }
}

// fully parallel: above-boundary -> accumulate; boundary bin -> list
__global__ __launch_bounds__(256) void k_accum(
    const float* __restrict__ cls, const float* __restrict__ del,
    const float* __restrict__ gt, uint8_t* ws) {
  int n = blockIdx.y;
  int a = blockIdx.x * blockDim.x + threadIdx.x;
  if (a >= A_TOT) return;
  const int* match = (const int*)(ws + OFF_MATCH);
  const uint32_t* posb = (const uint32_t*)(ws + OFF_POSB);
  const uint32_t* negb = (const uint32_t*)(ws + OFF_NEGB);
  const int* thr = (const int*)(ws + OFF_THR);
  int* cnt = (int*)(ws + OFF_CNT);
  unsigned long long* bnd = (unsigned long long*)(ws + OFF_BND);
  float* acc = (float*)(ws + OFF_ACC) + n * 4;
  int bPos = thr[(n * 2 + 0) * 3];
  int bNeg = thr[(n * 2 + 1) * 3];

  uint32_t pb = posb[n * A_TOT + a];
  if (pb) {
    int bin = (int)(pb >> 11);
    if (bPos < 0 || bin > bPos) {
      accum_pos(n, a, cls, del, gt, match, acc);
    } else if (bin == bPos) {
      int i = atomicAdd(&cnt[n * 2 + 0], 1);
      if (i < CAP)
        bnd[(n * 2 + 0) * CAP + i] =
            ((unsigned long long)pb << 17) | (unsigned)(0x1FFFF - a);
    }
  }
  uint32_t nb = negb[n * A_TOT + a];
  if (nb) {
    int bin = (int)(nb >> 11);
    if (bNeg < 0 || bin > bNeg) {
      accum_neg(n, a, cls, acc);
    } else if (bin == bNeg) {
      int i = atomicAdd(&cnt[n * 2 + 1], 1);
      if (i < CAP)
        bnd[(n * 2 + 1) * CAP + i] =
            ((unsigned long long)nb << 17) | (unsigned)(0x1FFFF - a);
    }
  }
}

// one block per (which, image): exact top-`need` in boundary bin by rank count
__global__ __launch_bounds__(256) void k_bound(
    const float* __restrict__ cls, const float* __restrict__ del,
    const float* __restrict__ gt, uint8_t* ws) {
  int which = blockIdx.x, n = blockIdx.y, tid = threadIdx.x;
  const int* match = (const int*)(ws + OFF_MATCH);
  const int* thr = (const int*)(ws + OFF_THR);
  const int* cnt = (const int*)(ws + OFF_CNT);
  const unsigned long long* bnd =
      (const unsigned long long*)(ws + OFF_BND) + (n * 2 + which) * CAP;
  float* acc = (float*)(ws + OFF_ACC) + n * 4;
  int need = thr[(n * 2 + which) * 3 + 1];
  if (need <= 0) return;
  int m = min(cnt[n * 2 + which], CAP);
  __shared__ unsigned long long sb[CAP];
  for (int i = tid; i < m; i += 256) sb[i] = bnd[i];
  __syncthreads();
  for (int i = tid; i < m; i += 256) {
    unsigned long long key = sb[i];
    int rank = 0;
    for (int j = 0; j < m; ++j) rank += (sb[j] > key) ? 1 : 0;
    if (rank < need) {
      int aa = 0x1FFFF - (int)(key & 0x1FFFFull);
      if (which == 0) accum_pos(n, aa, cls, del, gt, match, acc);
      else            accum_neg(n, aa, cls, acc);
    }
  }
}

__global__ void k_final(const uint8_t* ws, float* out) {
  if (blockIdx.x == 0 && threadIdx.x == 0) {
    const float* acc = (const float*)(ws + OFF_ACC);
    const int* thr = (const int*)(ws + OFF_THR);
    float c = 0.f, b = 0.f, fg = 0.f, bg = 0.f, pm = 0.f;
    for (int n = 0; n < N_IMG; ++n) {
      float npos = (float)thr[(n * 2 + 0) * 3 + 2];
      float nneg = (float)thr[(n * 2 + 1) * 3 + 2];
      float denom = fmaxf(npos + nneg, 1.f);
      c += acc[n * 4 + 0] / denom;
      b += acc[n * 4 + 2] / (fmaxf(npos, 1.f) * 8.0f);
      fg += npos; bg += nneg;
      if (n == N_IMG - 1) pm = acc[n * 4 + 1] / denom;
    }
    out[0] = c;
    out[1] = b;
    out[2] = bg;
    out[3] = fg;
    out[4] = pm;
  }
}

extern "C" void kernel_launch(void* const* d_in, const int* in_sizes, int n_in,
                              void* d_out, int out_size, void* d_ws, size_t ws_size,
                              hipStream_t stream) {
  (void)in_sizes; (void)n_in; (void)out_size; (void)ws_size;
  const float* cls = (const float*)d_in[0];
  const float* del = (const float*)d_in[1];
  const float* gt  = (const float*)d_in[2];
  float* out = (float*)d_out;
  uint8_t* ws = (uint8_t*)d_ws;

  hipLaunchKernelGGL(k_init, dim3((ZERO_U32 + 255) / 256), dim3(256), 0, stream, ws);
  hipLaunchKernelGGL(k_match, dim3((A_TOT + 255) / 256, N_IMG), dim3(256), 0, stream,
                     cls, del, gt, ws);
  hipLaunchKernelGGL(k_thresh, dim3(2, N_IMG), dim3(256), 0, stream, ws);
  hipLaunchKernelGGL(k_accum, dim3((A_TOT + 255) / 256, N_IMG), dim3(256), 0, stream,
                     cls, del, gt, ws);
  hipLaunchKernelGGL(k_bound, dim3(2, N_IMG), dim3(256), 0, stream, cls, del, gt, ws);
  hipLaunchKernelGGL(k_final, dim3(1), dim3(64), 0, stream, ws, out);
}